// Round 3
// baseline (459.603 us; speedup 1.0000x reference)
//
#include <hip/hip_runtime.h>

#define D 64

__device__ __forceinline__ float lane_bcast(float v, int k) {
    return __int_as_float(__builtin_amdgcn_readlane(__float_as_int(v), k));
}

// ---------------- adjacency build: per-node linked list ----------------
// next[e] written coalesced; only scattered traffic is atomicExch on head (400 KB).

__global__ void build_kernel(const int* __restrict__ ei, int* __restrict__ head,
                             int* __restrict__ next, int E) {
    int e = blockIdx.x * blockDim.x + threadIdx.x;
    if (e < E) {
        int dst = ei[E + e];
        next[e] = atomicExch(&head[dst], e);
    }
}

// ---------------- fused SAGE layer ----------------
// out[n] = [relu]( mean_{s in N(n)} in[s] @ Wl^T + bl + in[n] @ Wr^T )
// One wave handles 4 nodes: quarter-wave q walks node (n0+q)'s chain, each of its
// 16 lanes accumulating a float4 slice of the 64-float row. Then the whole wave
// computes the 4 output rows via readlane broadcasts + LDS weight reads.

__global__ void __launch_bounds__(256) sage_kernel(
    const float* __restrict__ in, const int* __restrict__ head,
    const int* __restrict__ next, const int* __restrict__ esrc,
    const float* __restrict__ Wl, const float* __restrict__ bl,
    const float* __restrict__ Wr, float* __restrict__ out,
    int N, int relu) {
    __shared__ float wtl[D * D];   // wtl[k*64 + f] = Wl[f][k]
    __shared__ float wtr[D * D];
    int tid = threadIdx.x;
    for (int idx = tid; idx < D * D; idx += 256) {
        int f = idx & 63, k = idx >> 6;          // conflict-free LDS writes
        wtl[k * D + f] = Wl[f * D + k];
        wtr[k * D + f] = Wr[f * D + k];
    }
    __syncthreads();

    int lane = tid & 63;
    int q    = lane >> 4;    // which node of the 4
    int fl   = lane & 15;    // float4 slice within the row
    float bias = bl[lane];
    int gwave   = blockIdx.x * 4 + (tid >> 6);
    int nwaves  = gridDim.x * 4;
    int ngroups = (N + 3) >> 2;

    for (int t = gwave; t < ngroups; t += nwaves) {
        int n0 = t * 4;
        int node = n0 + q;
        int e = (node < N) ? head[node] : -1;
        float ax = 0.f, ay = 0.f, az = 0.f, aw = 0.f;
        int deg = 0;
        while (__any(e >= 0)) {
            if (e >= 0) {
                int s  = esrc[e];     // same addr across quarter -> 1 request
                int en = next[e];
                const float4 v = *((const float4*)(in + (size_t)s * D) + fl);
                ax += v.x; ay += v.y; az += v.z; aw += v.w;
                ++deg;
                e = en;
            }
        }
        float scale = (deg > 0) ? 1.0f / (float)deg : 0.0f;
        ax *= scale; ay *= scale; az *= scale; aw *= scale;

        // own rows for the root term (4 coalesced 256B row loads)
        float x0 = (n0     < N) ? in[(size_t)(n0    ) * D + lane] : 0.f;
        float x1 = (n0 + 1 < N) ? in[(size_t)(n0 + 1) * D + lane] : 0.f;
        float x2 = (n0 + 2 < N) ? in[(size_t)(n0 + 2) * D + lane] : 0.f;
        float x3 = (n0 + 3 < N) ? in[(size_t)(n0 + 3) * D + lane] : 0.f;

#pragma unroll
        for (int q2 = 0; q2 < 4; ++q2) {
            int n2 = n0 + q2;
            if (n2 >= N) break;
            float xr = (q2 == 0) ? x0 : (q2 == 1) ? x1 : (q2 == 2) ? x2 : x3;
            float c = bias;
#pragma unroll
            for (int j = 0; j < 16; ++j) {
                int sl = q2 * 16 + j;   // lane holding float4 j of node q2's agg row
                c += lane_bcast(ax, sl) * wtl[(4 * j + 0) * D + lane]
                   + lane_bcast(ay, sl) * wtl[(4 * j + 1) * D + lane]
                   + lane_bcast(az, sl) * wtl[(4 * j + 2) * D + lane]
                   + lane_bcast(aw, sl) * wtl[(4 * j + 3) * D + lane];
                c += lane_bcast(xr, 4 * j + 0) * wtr[(4 * j + 0) * D + lane]
                   + lane_bcast(xr, 4 * j + 1) * wtr[(4 * j + 1) * D + lane]
                   + lane_bcast(xr, 4 * j + 2) * wtr[(4 * j + 2) * D + lane]
                   + lane_bcast(xr, 4 * j + 3) * wtr[(4 * j + 3) * D + lane];
            }
            if (relu) c = fmaxf(c, 0.f);
            out[(size_t)n2 * D + lane] = c;
        }
    }
}

extern "C" void kernel_launch(void* const* d_in, const int* in_sizes, int n_in,
                              void* d_out, int out_size, void* d_ws, size_t ws_size,
                              hipStream_t stream) {
    const float* x   = (const float*)d_in[0];
    const int*   ei  = (const int*)d_in[1];
    const float* W1l = (const float*)d_in[2];
    const float* b1l = (const float*)d_in[3];
    const float* W1r = (const float*)d_in[4];
    const float* W2l = (const float*)d_in[5];
    const float* b2l = (const float*)d_in[6];
    const float* W2r = (const float*)d_in[7];
    float* out = (float*)d_out;

    int N = in_sizes[0] / D;   // 100000
    int E = in_sizes[1] / 2;   // 1000000

    char* ws = (char*)d_ws;
    float* h    = (float*)ws;                       // N*D floats (layer-1 output)
    int*   head = (int*)(ws + (size_t)N * D * 4);   // N ints
    int*   next = head + N;                         // E ints

    hipMemsetAsync(head, 0xFF, (size_t)N * 4, stream);   // head = -1

    int eblocks = (E + 255) / 256;
    build_kernel<<<eblocks, 256, 0, stream>>>(ei, head, next, E);

    // layer 1: h = relu(mean_agg(x)@W1l^T + b1l + x@W1r^T)
    sage_kernel<<<1280, 256, 0, stream>>>(x, head, next, ei, W1l, b1l, W1r, h, N, 1);
    // layer 2: out = mean_agg(h)@W2l^T + b2l + h@W2r^T
    sage_kernel<<<1280, 256, 0, stream>>>(h, head, next, ei, W2l, b2l, W2r, out, N, 0);
}

// Round 4
// 388.710 us; speedup vs baseline: 1.1824x; 1.1824x over previous
//
#include <hip/hip_runtime.h>

#define D 64

__device__ __forceinline__ float lane_bcast(float v, int k) {
    return __int_as_float(__builtin_amdgcn_readlane(__float_as_int(v), k));
}

// ---------------- adjacency build: per-node linked list ----------------

__global__ void build_kernel(const int* __restrict__ ei, int* __restrict__ head,
                             int* __restrict__ next, int E) {
    int e = blockIdx.x * blockDim.x + threadIdx.x;
    if (e < E) next[e] = atomicExch(&head[ei[E + e]], e);
}

// thread per node: walk chain for degree, then wave-scan bump-allocate CSR slice
__global__ void alloc_kernel(const int* __restrict__ head, const int* __restrict__ next,
                             int* __restrict__ beg, int* __restrict__ cnt,
                             int* __restrict__ total, int N) {
    int i = blockIdx.x * blockDim.x + threadIdx.x;
    int lane = threadIdx.x & 63;
    int c = 0;
    if (i < N) {
        int e = head[i];
        while (e >= 0) { ++c; e = next[e]; }
    }
    int p = c;
#pragma unroll
    for (int o = 1; o < 64; o <<= 1) {
        int u = __shfl_up(p, o, 64);
        if (lane >= o) p += u;
    }
    int wavetot = __shfl(p, 63, 64);
    int base = 0;
    if (lane == 63) base = atomicAdd(total, wavetot);
    base = __shfl(base, 63, 64);
    if (i < N) { beg[i] = base + p - c; cnt[i] = c; }
}

// thread per node: walk chain, write contiguous srclist slice (sequential stores)
__global__ void fill_kernel(const int* __restrict__ ei, const int* __restrict__ head,
                            const int* __restrict__ next, const int* __restrict__ beg,
                            int* __restrict__ srclist, int N) {
    int i = blockIdx.x * blockDim.x + threadIdx.x;
    if (i >= N) return;
    int e = head[i];
    int p = beg[i];
    while (e >= 0) { srclist[p++] = ei[e]; e = next[e]; }
}

// ---------------- fused SAGE layer ----------------
// out[n] = [relu]( mean_{s in N(n)} in[s] @ Wl^T + bl + in[n] @ Wr^T )
// Quarter-wave q owns node n0+q; its 16 lanes each hold a float4 slice of the
// 64-float row. CSR gather: clamped-index, mask-multiplied, unrolled x4 ->
// up to 16 independent row loads in flight per wave.

__global__ void __launch_bounds__(256) sage_kernel(
    const float* __restrict__ in, const int* __restrict__ beg_,
    const int* __restrict__ cnt_, const int* __restrict__ srclist,
    const float* __restrict__ Wl, const float* __restrict__ bl,
    const float* __restrict__ Wr, float* __restrict__ out,
    int N, int relu) {
    __shared__ float wtl[D * D];   // wtl[k*64 + f] = Wl[f][k]
    __shared__ float wtr[D * D];
    int tid = threadIdx.x;
    for (int idx = tid; idx < D * D; idx += 256) {
        int f = idx & 63, k = idx >> 6;
        wtl[k * D + f] = Wl[f * D + k];
        wtr[k * D + f] = Wr[f * D + k];
    }
    __syncthreads();

    int lane = tid & 63;
    int q    = lane >> 4;    // which node of the 4
    int fl   = lane & 15;    // float4 slice within the row
    float bias = bl[lane];
    int gwave   = blockIdx.x * 4 + (tid >> 6);
    int nwaves  = gridDim.x * 4;
    int ngroups = (N + 3) >> 2;

    for (int t = gwave; t < ngroups; t += nwaves) {
        int n0 = t * 4;
        int node = n0 + q;
        bool nv = node < N;
        int beg = nv ? beg_[node] : 0;   // 16 lanes same addr -> 1 request
        int deg = nv ? cnt_[node] : 0;

        float ax = 0.f, ay = 0.f, az = 0.f, aw = 0.f;
        for (int j = 0; j < deg; j += 4) {
#pragma unroll
            for (int u = 0; u < 4; ++u) {
                int jj = j + u;
                int idx = beg + ((jj < deg) ? jj : (deg - 1));
                int si = srclist[idx];
                const float4 v = *((const float4*)(in + (size_t)si * D) + fl);
                float m = (jj < deg) ? 1.f : 0.f;
                ax = fmaf(m, v.x, ax); ay = fmaf(m, v.y, ay);
                az = fmaf(m, v.z, az); aw = fmaf(m, v.w, aw);
            }
        }
        float scale = (deg > 0) ? 1.0f / (float)deg : 0.0f;
        ax *= scale; ay *= scale; az *= scale; aw *= scale;

        // root rows (coalesced 256B row loads)
        float x0 = (n0     < N) ? in[(size_t)(n0    ) * D + lane] : 0.f;
        float x1 = (n0 + 1 < N) ? in[(size_t)(n0 + 1) * D + lane] : 0.f;
        float x2 = (n0 + 2 < N) ? in[(size_t)(n0 + 2) * D + lane] : 0.f;
        float x3 = (n0 + 3 < N) ? in[(size_t)(n0 + 3) * D + lane] : 0.f;

#pragma unroll
        for (int q2 = 0; q2 < 4; ++q2) {
            int n2 = n0 + q2;
            if (n2 >= N) break;
            float xr = (q2 == 0) ? x0 : (q2 == 1) ? x1 : (q2 == 2) ? x2 : x3;
            float c = bias;
#pragma unroll
            for (int j = 0; j < 16; ++j) {
                int sl = q2 * 16 + j;   // lane holding float4 j of node q2's agg row
                c += lane_bcast(ax, sl) * wtl[(4 * j + 0) * D + lane]
                   + lane_bcast(ay, sl) * wtl[(4 * j + 1) * D + lane]
                   + lane_bcast(az, sl) * wtl[(4 * j + 2) * D + lane]
                   + lane_bcast(aw, sl) * wtl[(4 * j + 3) * D + lane];
                c += lane_bcast(xr, 4 * j + 0) * wtr[(4 * j + 0) * D + lane]
                   + lane_bcast(xr, 4 * j + 1) * wtr[(4 * j + 1) * D + lane]
                   + lane_bcast(xr, 4 * j + 2) * wtr[(4 * j + 2) * D + lane]
                   + lane_bcast(xr, 4 * j + 3) * wtr[(4 * j + 3) * D + lane];
            }
            if (relu) c = fmaxf(c, 0.f);
            out[(size_t)n2 * D + lane] = c;
        }
    }
}

extern "C" void kernel_launch(void* const* d_in, const int* in_sizes, int n_in,
                              void* d_out, int out_size, void* d_ws, size_t ws_size,
                              hipStream_t stream) {
    const float* x   = (const float*)d_in[0];
    const int*   ei  = (const int*)d_in[1];
    const float* W1l = (const float*)d_in[2];
    const float* b1l = (const float*)d_in[3];
    const float* W1r = (const float*)d_in[4];
    const float* W2l = (const float*)d_in[5];
    const float* b2l = (const float*)d_in[6];
    const float* W2r = (const float*)d_in[7];
    float* out = (float*)d_out;

    int N = in_sizes[0] / D;   // 100000
    int E = in_sizes[1] / 2;   // 1000000

    char* ws = (char*)d_ws;
    // h occupies [0, N*D*4); head/next alias its first 4.4 MB during the build
    // phase (dead before sage1 writes h).
    float* h       = (float*)ws;
    int*   head    = (int*)ws;                        // N ints (aliases h)
    int*   next    = head + N;                        // E ints (aliases h)
    int*   srclist = (int*)(ws + (size_t)N * D * 4);  // E ints
    int*   beg     = srclist + E;                     // N ints
    int*   cnt     = beg + N;                         // N ints
    int*   total   = cnt + N;                         // 1 int

    hipMemsetAsync(head, 0xFF, (size_t)N * 4, stream);              // head = -1
    hipMemsetAsync(total, 0, 4, stream);

    int eblocks = (E + 255) / 256;
    int nblocks = (N + 255) / 256;
    build_kernel<<<eblocks, 256, 0, stream>>>(ei, head, next, E);
    alloc_kernel<<<nblocks, 256, 0, stream>>>(head, next, beg, cnt, total, N);
    fill_kernel<<<nblocks, 256, 0, stream>>>(ei, head, next, beg, srclist, N);

    // layer 1: h = relu(mean_agg(x)@W1l^T + b1l + x@W1r^T)
    sage_kernel<<<1280, 256, 0, stream>>>(x, beg, cnt, srclist, W1l, b1l, W1r, h, N, 1);
    // layer 2: out = mean_agg(h)@W2l^T + b2l + h@W2r^T
    sage_kernel<<<1280, 256, 0, stream>>>(h, beg, cnt, srclist, W2l, b2l, W2r, out, N, 0);
}